// Round 3
// baseline (322.514 us; speedup 1.0000x reference)
//
#include <hip/hip_runtime.h>

typedef unsigned short u16;
typedef unsigned int u32;
typedef __attribute__((ext_vector_type(8))) short short8;   // 8 bf16 (4 VGPRs)
typedef __attribute__((ext_vector_type(4))) float floatx4;  // MFMA accumulator

__device__ __forceinline__ u16 f2bf(float f) {
  u32 u = __float_as_uint(f);
  u32 r = u + 0x7fffu + ((u >> 16) & 1u);   // round-to-nearest-even
  return (u16)(r >> 16);
}

// async global->LDS, 16B per lane. lds ptr must be wave-uniform base; HW
// writes lane i at base + i*16.
__device__ __forceinline__ void gload_lds16(const u16* g, u16* l) {
  __builtin_amdgcn_global_load_lds(
      (const __attribute__((address_space(1))) u32*)g,
      (__attribute__((address_space(3))) u32*)l, 16, 0, 0);
}

// ---------------------------------------------------------------------------
// Fused cast (fp32->bf16) + transpose. in: [rows, cols] fp32 (per batch).
// cast_out (optional): bf16 same layout. tr_out: bf16 [cols, rows].
// ---------------------------------------------------------------------------
__global__ __launch_bounds__(256)
void cast_tr(const float* __restrict__ in, u16* __restrict__ cast_out,
             u16* __restrict__ tr_out, int rows, int cols, float scale,
             long bstride)
{
  __shared__ u16 tile[64][65];
  const int b = blockIdx.z;
  in += (long)b * bstride;
  if (cast_out) cast_out += (long)b * bstride;
  tr_out += (long)b * bstride;
  const int r0 = blockIdx.y * 64, c0 = blockIdx.x * 64;
  const int tx = threadIdx.x & 63, ty = threadIdx.x >> 6;

  for (int i = ty; i < 64; i += 4) {
    float v = in[(long)(r0 + i) * cols + c0 + tx] * scale;
    u16 h = f2bf(v);
    if (cast_out) cast_out[(long)(r0 + i) * cols + c0 + tx] = h;
    tile[i][tx] = h;
  }
  __syncthreads();
  for (int i = ty; i < 64; i += 4)
    tr_out[(long)(c0 + i) * rows + r0 + tx] = tile[tx][i];
}

// ---------------------------------------------------------------------------
// NT GEMM: C[M,N] = A[M,K] * Bt[N,K]^T, bf16 inputs, fp32 accumulate.
// Block tile = (MI*32) x (NJ*32), BK=64. 4 waves in 2x2; each wave MIxNJ
// tiles of 16x16x32 MFMA. LDS staged via global_load_lds(16B) with XOR
// chunk swizzle. GROUP_M=8 pid swizzle for L2 strip reuse.
// MODE 0: plain bf16 out.
// MODE 1: bf16 out = exp(acc*escale); fp32 row sums into rsum (atomics).
// MODE 2: fp32 out = acc / rsum[row] + bias[col].
// ---------------------------------------------------------------------------
#define BK 64

template<int MODE, int MI, int NJ>
__global__ __launch_bounds__(256, 3)
void gemm_nt(const u16* __restrict__ A, const u16* __restrict__ Bt,
             void* __restrict__ Cout, const float* __restrict__ bias,
             float* __restrict__ rsum,
             int M, int N, int K, int lda, int ldb, int ldc,
             long sA, long sB, long sC, float escale)
{
  constexpr int BM = MI * 32;
  constexpr int BN = NJ * 32;
  __shared__ __align__(16) u16 As[BM * BK];
  __shared__ __align__(16) u16 Bs[BN * BK];

  const int bz = blockIdx.z;
  A  += (long)bz * sA;
  Bt += (long)bz * sB;

  const int tid  = threadIdx.x;
  const int wave = tid >> 6;
  const int lane = tid & 63;

  // GROUP_M=8 swizzle
  const int nbx = gridDim.x, nby = gridDim.y;
  const int pid  = blockIdx.y * nbx + blockIdx.x;
  const int band = 8 * nbx;
  const int gid  = pid / band;
  const int fm   = gid * 8;
  const int gsz  = min(nby - fm, 8);
  const int pm   = fm + (pid % band) % gsz;
  const int pn   = (pid % band) / gsz;
  const int tileM = pm * BM;
  const int tileN = pn * BN;

  // staging: per instruction a wave covers 8 rows x 8 chunks (16B each)
  const int srow = lane >> 3;      // 0..7 row within 8-row group
  const int sj   = lane & 7;       // 0..7 dest chunk
  const int sjj  = sj ^ srow;      // swizzled source chunk

  // wave quadrant + mfma lane coords
  const int wm = (wave >> 1) * (MI * 16);
  const int wn = (wave & 1) * (NJ * 16);
  const int lc = lane & 15;        // A row / B col / C col
  const int lq = lane >> 4;        // quad

  floatx4 acc[MI][NJ];
  #pragma unroll
  for (int i = 0; i < MI; ++i)
    #pragma unroll
    for (int j = 0; j < NJ; ++j)
      acc[i][j] = (floatx4){0.f, 0.f, 0.f, 0.f};

  for (int k0 = 0; k0 < K; k0 += BK) {
    #pragma unroll
    for (int s = 0; s < MI; ++s) {
      const int rb = (wave * MI + s) * 8;
      gload_lds16(A + (long)(tileM + rb + srow) * lda + k0 + sjj * 8,
                  &As[rb * BK]);
    }
    #pragma unroll
    for (int s = 0; s < NJ; ++s) {
      const int rb = (wave * NJ + s) * 8;
      gload_lds16(Bt + (long)(tileN + rb + srow) * ldb + k0 + sjj * 8,
                  &Bs[rb * BK]);
    }
    __syncthreads();   // drains vmcnt(0) -> LDS valid

    #pragma unroll
    for (int kk = 0; kk < BK; kk += 32) {
      const int jcb = (kk >> 3) + lq;       // logical chunk for this quad
      short8 af[MI], bf[NJ];
      #pragma unroll
      for (int i = 0; i < MI; ++i) {
        const int m = wm + i * 16 + lc;
        af[i] = *(const short8*)&As[m * BK + ((jcb ^ (m & 7)) << 3)];
      }
      #pragma unroll
      for (int j = 0; j < NJ; ++j) {
        const int n = wn + j * 16 + lc;
        bf[j] = *(const short8*)&Bs[n * BK + ((jcb ^ (n & 7)) << 3)];
      }
      #pragma unroll
      for (int i = 0; i < MI; ++i)
        #pragma unroll
        for (int j = 0; j < NJ; ++j)
          acc[i][j] = __builtin_amdgcn_mfma_f32_16x16x32_bf16(
                          af[i], bf[j], acc[i][j], 0, 0, 0);
    }
    __syncthreads();   // protect LDS before next stage
  }

  // epilogue: C/D layout col = lane&15, row = quad*4 + reg
  if (MODE == 0) {
    u16* C = (u16*)Cout + (long)bz * sC;
    #pragma unroll
    for (int i = 0; i < MI; ++i) {
      const int rb = tileM + wm + i * 16 + lq * 4;
      #pragma unroll
      for (int j = 0; j < NJ; ++j) {
        const int col = tileN + wn + j * 16 + lc;
        #pragma unroll
        for (int r = 0; r < 4; ++r)
          C[(long)(rb + r) * ldc + col] = f2bf(acc[i][j][r]);
      }
    }
  } else if (MODE == 1) {
    u16* C = (u16*)Cout + (long)bz * sC;
    float* rs = rsum + (long)bz * M;
    #pragma unroll
    for (int i = 0; i < MI; ++i) {
      const int rb = tileM + wm + i * 16 + lq * 4;
      float rpart[4] = {0.f, 0.f, 0.f, 0.f};
      #pragma unroll
      for (int j = 0; j < NJ; ++j) {
        const int col = tileN + wn + j * 16 + lc;
        #pragma unroll
        for (int r = 0; r < 4; ++r) {
          float e = __expf(acc[i][j][r] * escale);
          C[(long)(rb + r) * ldc + col] = f2bf(e);
          rpart[r] += e;
        }
      }
      #pragma unroll
      for (int r = 0; r < 4; ++r) {
        float s = rpart[r];
        s += __shfl_xor(s, 1, 64);
        s += __shfl_xor(s, 2, 64);
        s += __shfl_xor(s, 4, 64);
        s += __shfl_xor(s, 8, 64);
        if (lc == 0) atomicAdd(&rs[rb + r], s);
      }
    }
  } else {
    float* C = (float*)Cout + (long)bz * sC;
    const float* rs = rsum + (long)bz * M;
    #pragma unroll
    for (int i = 0; i < MI; ++i) {
      const int rb = tileM + wm + i * 16 + lq * 4;
      float inv[4];
      #pragma unroll
      for (int r = 0; r < 4; ++r) inv[r] = 1.0f / rs[rb + r];
      #pragma unroll
      for (int j = 0; j < NJ; ++j) {
        const int col = tileN + wn + j * 16 + lc;
        const float bv = bias[col];
        #pragma unroll
        for (int r = 0; r < 4; ++r)
          C[(long)(rb + r) * ldc + col] = acc[i][j][r] * inv[r] + bv;
      }
    }
  }
}

// ---------------------------------------------------------------------------
extern "C" void kernel_launch(void* const* d_in, const int* in_sizes, int n_in,
                              void* d_out, int out_size, void* d_ws, size_t ws_size,
                              hipStream_t stream) {
  const float* x    = (const float*)d_in[0];   // [B,S,D] fp32
  const float* W    = (const float*)d_in[1];   // [D,D]   fp32
  const float* bias = (const float*)d_in[2];   // [D]     fp32
  float* out        = (float*)d_out;           // [B,S,D] fp32
  (void)in_sizes; (void)n_in; (void)out_size; (void)ws_size;

  const int B = 8, S = 2048, D = 1024;
  const long BSD = (long)B * S * D;            // 16,777,216

  // workspace layout (u16 elements): ~162 MiB + 64 KiB row sums
  u16* Xb  = (u16*)d_ws;            // [B,S,D] bf16 (x)
  u16* XbT = Xb  + BSD;             // [B,D,S] bf16 (x transposed per batch)
  u16* Qb  = XbT + BSD;             // [B,S,D] bf16 (Q, pre-scaled by 1/32)
  u16* Wt  = Qb  + BSD;             // [D,D]   bf16 (W^T * 1/sqrt(D))
  u16* Sc  = Wt  + (long)D * D;     // [B,S,S] bf16 (E = exp(scores), unnorm)
  float* rsum = (float*)(Sc + (long)B * S * S);  // [B,S] fp32 row sums

  dim3 blk(256);

  // zero row sums (re-poisoned to 0xAA before every timed call)
  hipMemsetAsync(rsum, 0, (size_t)B * S * sizeof(float), stream);

  // x -> Xb + XbT (scale 1), W -> Wt (scale 1/32 folded into Q)
  cast_tr<<<dim3(D/64, S/64, B), blk, 0, stream>>>(x, Xb, XbT, S, D, 1.0f, (long)S*D);
  cast_tr<<<dim3(D/64, D/64, 1), blk, 0, stream>>>(W, nullptr, Wt, D, D, 0.03125f, 0);

  // GEMM1: Qb[BS,D] = Xb[BS,D] @ Wt[D,D]^T   (batches flattened)
  // 64x128 tile -> 2048 blocks (vs 1024 at 128x128): kills the 2-round
  // wave-quantization stall (768 co-resident block slots on 256 CUs).
  gemm_nt<0, 2, 4><<<dim3(D/128, (B*S)/64, 1), blk, 0, stream>>>(
      Xb, Wt, Qb, nullptr, nullptr, B*S, D, D, D, D, D, 0, 0, 0, 1.0f);

  // GEMM2: Sc[S,S] = exp(Qb[S,D] @ Xb[S,D]^T), rsum += row sums  per batch
  gemm_nt<1, 4, 4><<<dim3(S/128, S/128, B), blk, 0, stream>>>(
      Qb, Xb, Sc, nullptr, rsum, S, S, D, D, D, S,
      (long)S*D, (long)S*D, (long)S*S, 1.0f);

  // GEMM3: out[S,D] = (Sc/rsum)[S,S] @ XbT[D,S]^T + bias  per batch, fp32 out
  gemm_nt<2, 4, 4><<<dim3(D/128, S/128, B), blk, 0, stream>>>(
      Sc, XbT, out, bias, rsum, S, D, S, S, S, D,
      (long)S*S, (long)D*S, (long)S*D, 1.0f);
}

// Round 4
// 305.051 us; speedup vs baseline: 1.0572x; 1.0572x over previous
//
#include <hip/hip_runtime.h>

typedef unsigned short u16;
typedef unsigned int u32;
typedef __attribute__((ext_vector_type(8))) short short8;   // 8 bf16 (4 VGPRs)
typedef __attribute__((ext_vector_type(4))) float floatx4;  // MFMA accumulator

__device__ __forceinline__ u16 f2bf(float f) {
  u32 u = __float_as_uint(f);
  u32 r = u + 0x7fffu + ((u >> 16) & 1u);   // round-to-nearest-even
  return (u16)(r >> 16);
}

// async global->LDS, 16B per lane. lds ptr must be wave-uniform base; HW
// writes lane i at base + i*16.
__device__ __forceinline__ void gload_lds16(const u16* g, u16* l) {
  __builtin_amdgcn_global_load_lds(
      (const __attribute__((address_space(1))) u32*)g,
      (__attribute__((address_space(3))) u32*)l, 16, 0, 0);
}

// ---------------------------------------------------------------------------
// Fused cast (fp32->bf16) + transpose, vectorized. in: [rows, cols] fp32.
// cast_out (optional): bf16 same layout (ushort4 stores).
// tr_out: bf16 [cols, rows] (u32 = 2-element stores, coalesced along rows).
// Tile 64x64, 256 threads.
// ---------------------------------------------------------------------------
__global__ __launch_bounds__(256)
void cast_tr(const float* __restrict__ in, u16* __restrict__ cast_out,
             u16* __restrict__ tr_out, int rows, int cols, float scale,
             long bstride)
{
  // transposed tile: tileT[src_col][src_row], pad 66 (132B row, 33-bank shift)
  __shared__ u16 tileT[64][66];
  const int b = blockIdx.z;
  in += (long)b * bstride;
  if (cast_out) cast_out += (long)b * bstride;
  tr_out += (long)b * bstride;
  const int r0 = blockIdx.y * 64, c0 = blockIdx.x * 64;
  const int tid = threadIdx.x;

  // phase 1: read float4, cast, store ushort4, scatter to tileT
  {
    const int i0 = tid >> 4;          // 0..15 row group
    const int c4 = (tid & 15) * 4;    // col group of 4
    #pragma unroll
    for (int rr = 0; rr < 4; ++rr) {
      const int r = i0 + 16 * rr;
      const float4 v = *(const float4*)&in[(long)(r0 + r) * cols + c0 + c4];
      ushort4 h;
      h.x = f2bf(v.x * scale); h.y = f2bf(v.y * scale);
      h.z = f2bf(v.z * scale); h.w = f2bf(v.w * scale);
      if (cast_out)
        *(ushort4*)&cast_out[(long)(r0 + r) * cols + c0 + c4] = h;
      tileT[c4 + 0][r] = h.x;
      tileT[c4 + 1][r] = h.y;
      tileT[c4 + 2][r] = h.z;
      tileT[c4 + 3][r] = h.w;
    }
  }
  __syncthreads();

  // phase 2: write transposed, u32 (2 bf16) per store, lanes walk rows fast
  {
    const int cb = tid >> 5;          // 0..7
    const int rh = tid & 31;          // 0..31 (u32 position within 64 rows)
    #pragma unroll
    for (int m = 0; m < 8; ++m) {
      const int c = cb * 8 + m;
      const u32 pair = *(const u32*)&tileT[c][rh * 2];
      *(u32*)&tr_out[(long)(c0 + c) * rows + r0 + rh * 2] = pair;
    }
  }
}

// ---------------------------------------------------------------------------
// NT GEMM: C[M,N] = A[M,K] * Bt[N,K]^T, bf16 inputs, fp32 accumulate.
// Block tile = (MI*32) x (NJ*32), BK=64. 4 waves in 2x2; each wave MIxNJ
// tiles of 16x16x32 MFMA. LDS staged via global_load_lds(16B) with XOR
// chunk swizzle. GROUP_M=8 pid swizzle for L2 strip reuse.
// MODE 0: plain bf16 out.
// MODE 1: bf16 out = exp(acc*escale); fp32 row sums into rsum (atomics).
// MODE 2: fp32 out = acc / rsum[row] + bias[col].
// ---------------------------------------------------------------------------
#define BK 64

template<int MODE, int MI, int NJ>
__global__ __launch_bounds__(256, 3)
void gemm_nt(const u16* __restrict__ A, const u16* __restrict__ Bt,
             void* __restrict__ Cout, const float* __restrict__ bias,
             float* __restrict__ rsum,
             int M, int N, int K, int lda, int ldb, int ldc,
             long sA, long sB, long sC, float escale)
{
  constexpr int BM = MI * 32;
  constexpr int BN = NJ * 32;
  __shared__ __align__(16) u16 As[BM * BK];
  __shared__ __align__(16) u16 Bs[BN * BK];

  const int bz = blockIdx.z;
  A  += (long)bz * sA;
  Bt += (long)bz * sB;

  const int tid  = threadIdx.x;
  const int wave = tid >> 6;
  const int lane = tid & 63;

  // GROUP_M=8 swizzle
  const int nbx = gridDim.x, nby = gridDim.y;
  const int pid  = blockIdx.y * nbx + blockIdx.x;
  const int band = 8 * nbx;
  const int gid  = pid / band;
  const int fm   = gid * 8;
  const int gsz  = min(nby - fm, 8);
  const int pm   = fm + (pid % band) % gsz;
  const int pn   = (pid % band) / gsz;
  const int tileM = pm * BM;
  const int tileN = pn * BN;

  // staging: per instruction a wave covers 8 rows x 8 chunks (16B each)
  const int srow = lane >> 3;      // 0..7 row within 8-row group
  const int sj   = lane & 7;       // 0..7 dest chunk
  const int sjj  = sj ^ srow;      // swizzled source chunk

  // wave quadrant + mfma lane coords
  const int wm = (wave >> 1) * (MI * 16);
  const int wn = (wave & 1) * (NJ * 16);
  const int lc = lane & 15;        // A row / B col / C col
  const int lq = lane >> 4;        // quad

  floatx4 acc[MI][NJ];
  #pragma unroll
  for (int i = 0; i < MI; ++i)
    #pragma unroll
    for (int j = 0; j < NJ; ++j)
      acc[i][j] = (floatx4){0.f, 0.f, 0.f, 0.f};

  for (int k0 = 0; k0 < K; k0 += BK) {
    #pragma unroll
    for (int s = 0; s < MI; ++s) {
      const int rb = (wave * MI + s) * 8;
      gload_lds16(A + (long)(tileM + rb + srow) * lda + k0 + sjj * 8,
                  &As[rb * BK]);
    }
    #pragma unroll
    for (int s = 0; s < NJ; ++s) {
      const int rb = (wave * NJ + s) * 8;
      gload_lds16(Bt + (long)(tileN + rb + srow) * ldb + k0 + sjj * 8,
                  &Bs[rb * BK]);
    }
    __syncthreads();   // drains vmcnt(0) -> LDS valid

    #pragma unroll
    for (int kk = 0; kk < BK; kk += 32) {
      const int jcb = (kk >> 3) + lq;       // logical chunk for this quad
      short8 af[MI], bf[NJ];
      #pragma unroll
      for (int i = 0; i < MI; ++i) {
        const int m = wm + i * 16 + lc;
        af[i] = *(const short8*)&As[m * BK + ((jcb ^ (m & 7)) << 3)];
      }
      #pragma unroll
      for (int j = 0; j < NJ; ++j) {
        const int n = wn + j * 16 + lc;
        bf[j] = *(const short8*)&Bs[n * BK + ((jcb ^ (n & 7)) << 3)];
      }
      #pragma unroll
      for (int i = 0; i < MI; ++i)
        #pragma unroll
        for (int j = 0; j < NJ; ++j)
          acc[i][j] = __builtin_amdgcn_mfma_f32_16x16x32_bf16(
                          af[i], bf[j], acc[i][j], 0, 0, 0);
    }
    __syncthreads();   // protect LDS before next stage
  }

  // epilogue: C/D layout col = lane&15, row = quad*4 + reg
  if (MODE == 0) {
    u16* C = (u16*)Cout + (long)bz * sC;
    #pragma unroll
    for (int i = 0; i < MI; ++i) {
      const int rb = tileM + wm + i * 16 + lq * 4;
      #pragma unroll
      for (int j = 0; j < NJ; ++j) {
        const int col = tileN + wn + j * 16 + lc;
        #pragma unroll
        for (int r = 0; r < 4; ++r)
          C[(long)(rb + r) * ldc + col] = f2bf(acc[i][j][r]);
      }
    }
  } else if (MODE == 1) {
    u16* C = (u16*)Cout + (long)bz * sC;
    float* rs = rsum + (long)bz * M;
    #pragma unroll
    for (int i = 0; i < MI; ++i) {
      const int rb = tileM + wm + i * 16 + lq * 4;
      float rpart[4] = {0.f, 0.f, 0.f, 0.f};
      #pragma unroll
      for (int j = 0; j < NJ; ++j) {
        const int col = tileN + wn + j * 16 + lc;
        #pragma unroll
        for (int r = 0; r < 4; ++r) {
          float e = __expf(acc[i][j][r] * escale);
          C[(long)(rb + r) * ldc + col] = f2bf(e);
          rpart[r] += e;
        }
      }
      #pragma unroll
      for (int r = 0; r < 4; ++r) {
        float s = rpart[r];
        s += __shfl_xor(s, 1, 64);
        s += __shfl_xor(s, 2, 64);
        s += __shfl_xor(s, 4, 64);
        s += __shfl_xor(s, 8, 64);
        if (lc == 0) atomicAdd(&rs[rb + r], s);
      }
    }
  } else {
    float* C = (float*)Cout + (long)bz * sC;
    const float* rs = rsum + (long)bz * M;
    #pragma unroll
    for (int i = 0; i < MI; ++i) {
      const int rb = tileM + wm + i * 16 + lq * 4;
      float inv[4];
      #pragma unroll
      for (int r = 0; r < 4; ++r) inv[r] = 1.0f / rs[rb + r];
      #pragma unroll
      for (int j = 0; j < NJ; ++j) {
        const int col = tileN + wn + j * 16 + lc;
        const float bv = bias[col];
        #pragma unroll
        for (int r = 0; r < 4; ++r)
          C[(long)(rb + r) * ldc + col] = acc[i][j][r] * inv[r] + bv;
      }
    }
  }
}

// ---------------------------------------------------------------------------
extern "C" void kernel_launch(void* const* d_in, const int* in_sizes, int n_in,
                              void* d_out, int out_size, void* d_ws, size_t ws_size,
                              hipStream_t stream) {
  const float* x    = (const float*)d_in[0];   // [B,S,D] fp32
  const float* W    = (const float*)d_in[1];   // [D,D]   fp32
  const float* bias = (const float*)d_in[2];   // [D]     fp32
  float* out        = (float*)d_out;           // [B,S,D] fp32
  (void)in_sizes; (void)n_in; (void)out_size; (void)ws_size;

  const int B = 8, S = 2048, D = 1024;
  const long BSD = (long)B * S * D;            // 16,777,216

  // workspace layout (u16 elements): ~162 MiB + 64 KiB row sums
  u16* Xb  = (u16*)d_ws;            // [B,S,D] bf16 (x)
  u16* XbT = Xb  + BSD;             // [B,D,S] bf16 (x transposed per batch)
  u16* Qb  = XbT + BSD;             // [B,S,D] bf16 (Q, pre-scaled by 1/32)
  u16* Wt  = Qb  + BSD;             // [D,D]   bf16 (W^T * 1/sqrt(D))
  u16* Sc  = Wt  + (long)D * D;     // [B,S,S] bf16 (E = exp(scores), unnorm)
  float* rsum = (float*)(Sc + (long)B * S * S);  // [B,S] fp32 row sums

  dim3 blk(256);

  // zero row sums (re-poisoned to 0xAA before every timed call)
  hipMemsetAsync(rsum, 0, (size_t)B * S * sizeof(float), stream);

  // x -> Xb + XbT (scale 1), W -> Wt (scale 1/32 folded into Q)
  cast_tr<<<dim3(D/64, S/64, B), blk, 0, stream>>>(x, Xb, XbT, S, D, 1.0f, (long)S*D);
  cast_tr<<<dim3(D/64, D/64, 1), blk, 0, stream>>>(W, nullptr, Wt, D, D, 0.03125f, 0);

  // GEMM1: Qb[BS,D] = Xb[BS,D] @ Wt[D,D]^T   (batches flattened)
  // 128x128 tile: 64x128 tried in R2 regressed (compute/staging intensity
  // drops 64 -> 42.7, GEMM1 became staging-bound; quantization win smaller).
  gemm_nt<0, 4, 4><<<dim3(D/128, (B*S)/128, 1), blk, 0, stream>>>(
      Xb, Wt, Qb, nullptr, nullptr, B*S, D, D, D, D, D, 0, 0, 0, 1.0f);

  // GEMM2: Sc[S,S] = exp(Qb[S,D] @ Xb[S,D]^T), rsum += row sums  per batch
  gemm_nt<1, 4, 4><<<dim3(S/128, S/128, B), blk, 0, stream>>>(
      Qb, Xb, Sc, nullptr, rsum, S, S, D, D, D, S,
      (long)S*D, (long)S*D, (long)S*S, 1.0f);

  // GEMM3: out[S,D] = (Sc/rsum)[S,S] @ XbT[D,S]^T + bias  per batch, fp32 out
  gemm_nt<2, 4, 4><<<dim3(D/128, S/128, B), blk, 0, stream>>>(
      Sc, XbT, out, bias, rsum, S, D, S, S, S, D,
      (long)S*S, (long)D*S, (long)S*D, 1.0f);
}